// Round 8
// baseline (88.523 us; speedup 1.0000x reference)
//
#include <hip/hip_runtime.h>
#include <hip/hip_bf16.h>
#include <math.h>

#define G 4
#define T 2048
#define H 1024
#define E 8
#define ZK1 2048  // K1: zero-fill blocks (issued first; 101MB dispatch half)
#define LGB 2048  // K1: logits blocks (4 token-waves each)
#define PB 48     // K1: gate pad-init blocks (48*256 == G*E*384)

typedef float f4 __attribute__((ext_vector_type(4)));
typedef unsigned long long u64;
typedef unsigned long long u64v2 __attribute__((ext_vector_type(2)));

// ---------------------------------------------------------------------------
// K1: [0,ZK1) zero dispatch half; [ZK1,ZK1+LGB) logits+softmax -> u64 keys
// (key = prob_bits<<32 | ~t : unique, desc == (value desc, idx asc) ==
// jax.lax.top_k); tail = gate pad-init (slots >= cap stay 0).
// fp64 numeric path FROZEN (absmax=0.0 R2-R6). Epilogue parallelized across
// lanes — bit-identical: butterfly leaves all lanes with all 8 accs; lane e
// does exp(l_e-m); 3-step shfl_xor sum == reference's exact add tree
// (fp add is bitwise commutative).
// ---------------------------------------------------------------------------
__global__ __launch_bounds__(256) void k1_zero_logits(
    const float* __restrict__ x, const float* __restrict__ W,
    const float* __restrict__ b, u64* __restrict__ keys,
    float* __restrict__ lse2, float* __restrict__ gate,
    float* __restrict__ out, unsigned n4d, int max_cap) {
  unsigned bid = blockIdx.x;
  unsigned tid = threadIdx.x;

  if (bid < ZK1) {
    f4* outD = (f4*)out;
    f4 z = {0.0f, 0.0f, 0.0f, 0.0f};
    unsigned stride = ZK1 * 256u;
    for (unsigned i = bid * 256u + tid; i < n4d; i += stride) outD[i] = z;
    return;
  }
  if (bid >= ZK1 + LGB) {
    unsigned s = (bid - ZK1 - LGB) * 256u + tid;
    if (s < (unsigned)(G * E * max_cap)) gate[s] = 0.0f;
    return;
  }

  int wave = (int)((bid - ZK1) * 4 + (tid >> 6));
  int lane = (int)(tid & 63);
  const float* xr = x + (size_t)wave * H;

  double acc0 = 0, acc1 = 0, acc2 = 0, acc3 = 0;
  double acc4 = 0, acc5 = 0, acc6 = 0, acc7 = 0;
#pragma unroll
  for (int j = 0; j < 4; ++j) {
    int hbase = j * 256 + lane * 4;
    f4 xv = *(const f4*)(xr + hbase);
#pragma unroll
    for (int k = 0; k < 4; ++k) {
      const float* wr = W + (size_t)(hbase + k) * 8;
      f4 w0 = *(const f4*)(wr);
      f4 w1 = *(const f4*)(wr + 4);
      double xd = (double)xv[k];
      acc0 += xd * (double)w0[0];
      acc1 += xd * (double)w0[1];
      acc2 += xd * (double)w0[2];
      acc3 += xd * (double)w0[3];
      acc4 += xd * (double)w1[0];
      acc5 += xd * (double)w1[1];
      acc6 += xd * (double)w1[2];
      acc7 += xd * (double)w1[3];
    }
  }
#pragma unroll
  for (int off = 32; off >= 1; off >>= 1) {
    acc0 += __shfl_xor(acc0, off);
    acc1 += __shfl_xor(acc1, off);
    acc2 += __shfl_xor(acc2, off);
    acc3 += __shfl_xor(acc3, off);
    acc4 += __shfl_xor(acc4, off);
    acc5 += __shfl_xor(acc5, off);
    acc6 += __shfl_xor(acc6, off);
    acc7 += __shfl_xor(acc7, off);
  }
  // every lane now has all 8 totals
  double l0 = acc0 + (double)b[0], l1 = acc1 + (double)b[1];
  double l2 = acc2 + (double)b[2], l3 = acc3 + (double)b[3];
  double l4 = acc4 + (double)b[4], l5 = acc5 + (double)b[5];
  double l6 = acc6 + (double)b[6], l7 = acc7 + (double)b[7];
  double m = fmax(fmax(fmax(l0, l1), fmax(l2, l3)),
                  fmax(fmax(l4, l5), fmax(l6, l7)));
  // branchless select l_{lane&7} (static names; no runtime-indexed array)
  double la = (lane & 1) ? l1 : l0;
  double lb = (lane & 1) ? l3 : l2;
  double lc = (lane & 1) ? l5 : l4;
  double ld = (lane & 1) ? l7 : l6;
  double le = (lane & 2) ? lb : la;
  double lf = (lane & 2) ? ld : lc;
  double lsel = (lane & 4) ? lf : le;

  double pe = exp(lsel - m);  // 8 exps in parallel (lanes 8-63 redundant)
  double s = pe;
  s += __shfl_xor(s, 1);
  s += __shfl_xor(s, 2);
  s += __shfl_xor(s, 4);  // == ((p0+p1)+(p2+p3))+((p4+p5)+(p6+p7)) bitwise
  double inv = 1.0 / s;
  float pf = (float)(pe * inv);

  int g = wave >> 11;
  int t = wave & (T - 1);
  if (lane < 8) {
    keys[((size_t)g * 8 + lane) * T + t] =
        ((u64)__float_as_uint(pf) << 32) | (unsigned)(~t);
  }
  if (lane == 0) {
    double lse = m + log(s);
    lse2[wave] = (float)(lse * lse);
  }
}

// ---------------------------------------------------------------------------
// K2: pure rank-select, 256 blocks (= 256 CUs), 1 token/thread. Stage 2048
// keys in LDS; broadcast ds_read_b128 scan with 4-deep prefetch + 4
// accumulators. Unique keys => rank == top_k slot. Winners write gate AND
// the dispatch 1.0 DIRECTLY (no idx/scatter roundtrip; dispatch was
// pre-zeroed in K1).
// ---------------------------------------------------------------------------
__global__ __launch_bounds__(256) void k2_rank(
    const u64* __restrict__ keys, float* __restrict__ gate,
    float* __restrict__ out, int max_cap, int ec) {
  __shared__ u64 lk[T];
  unsigned bid = blockIdx.x;
  unsigned tid = threadIdx.x;
  int ge = (int)(bid >> 3);
  int chunk = (int)(bid & 7);

  {
    const u64v2* src = (const u64v2*)(keys + (size_t)ge * T);
    u64v2* dst = (u64v2*)lk;
    for (int i = tid; i < T / 2; i += 256) dst[i] = src[i];
  }
  __syncthreads();

  int myt = chunk * 256 + (int)tid;
  u64 mine = lk[myt];

  const u64v2* k2p = (const u64v2*)lk;
  int r0 = 0, r1 = 0, r2 = 0, r3 = 0;
  u64v2 p0 = k2p[0], p1 = k2p[1], p2 = k2p[2], p3 = k2p[3];
  for (int j = 4; j < T / 2; j += 4) {
    u64v2 q0 = k2p[j], q1 = k2p[j + 1], q2 = k2p[j + 2], q3 = k2p[j + 3];
    r0 += (int)(p0.x > mine) + (int)(p0.y > mine);
    r1 += (int)(p1.x > mine) + (int)(p1.y > mine);
    r2 += (int)(p2.x > mine) + (int)(p2.y > mine);
    r3 += (int)(p3.x > mine) + (int)(p3.y > mine);
    p0 = q0;
    p1 = q1;
    p2 = q2;
    p3 = q3;
  }
  r0 += (int)(p0.x > mine) + (int)(p0.y > mine);
  r1 += (int)(p1.x > mine) + (int)(p1.y > mine);
  r2 += (int)(p2.x > mine) + (int)(p2.y > mine);
  r3 += (int)(p3.x > mine) + (int)(p3.y > mine);
  int rank = (r0 + r1) + (r2 + r3);

  const double factors[8] = {0.5, 0.75, 1.0, 1.0, 1.25, 1.25, 1.5, 1.5};
  int cap = (int)((double)ec * factors[ge & 7]);
  if (rank < cap) {
    gate[(size_t)ge * max_cap + rank] = __uint_as_float((unsigned)(mine >> 32));
    out[((size_t)ge * T + myt) * (unsigned)max_cap + rank] = 1.0f;
  }
}

// ---------------------------------------------------------------------------
// K3: block 0 = z-loss reduce + trailing scalars; rest = combine
// broadcast-fill (gate 48KB L1/L2-resident; pure f4 store stream, 101MB).
// ---------------------------------------------------------------------------
template <int MC4S>
__global__ __launch_bounds__(256) void k3_combine(
    const float* __restrict__ gate, const float* __restrict__ lse2,
    float* __restrict__ out, unsigned n4d, unsigned mc4_rt) {
  const unsigned mc4 = MC4S ? (unsigned)MC4S : mc4_rt;
  unsigned tid = threadIdx.x;
  unsigned bid = blockIdx.x;

  if (bid == 0) {
    __shared__ double red[256];
    double s = 0.0;
    for (int i = tid; i < G * T; i += 256) s += (double)lse2[i];
    red[tid] = s;
    __syncthreads();
    for (int off = 128; off > 0; off >>= 1) {
      if ((int)tid < off) red[tid] += red[tid + off];
      __syncthreads();
    }
    if (tid == 0) {
      size_t ne = (size_t)n4d * 4;
      out[2 * ne] = 0.0f;                                   // auxiliary_loss
      out[2 * ne + 1] = (float)(red[0] / (double)(G * T));  // z_loss
    }
    return;
  }

  f4* outC = (f4*)out + n4d;
  const f4* gate4 = (const f4*)gate;
  unsigned fb = bid - 1;
  unsigned nfb = gridDim.x - 1;
  unsigned stride = nfb * 256u;
  for (unsigned i = fb * 256u + tid; i < n4d; i += stride) {
    unsigned c4 = i % mc4;
    unsigned ge = (i / mc4) >> 11;  // row / T
    outC[i] = gate4[ge * mc4 + c4];
  }
}

extern "C" void kernel_launch(void* const* d_in, const int* in_sizes, int n_in,
                              void* d_out, int out_size, void* d_ws,
                              size_t ws_size, hipStream_t stream) {
  const float* x = (const float*)d_in[0];
  const float* W = (const float*)d_in[1];
  const float* b = (const float*)d_in[2];

  // Derive max_cap from out_size: out = 2*G*E*T*max_cap + 2 scalars.
  long long body = (long long)out_size - 2;
  int max_cap = (int)(body / (2LL * G * E * T));  // 384 for ec=256
  if (max_cap <= 0) return;
  int ec = (2 * max_cap) / 3;  // max factor is 1.5

  u64* keys = (u64*)d_ws;                            // 32*2048 u64 = 512 KB
  float* lse2 = (float*)(keys + (size_t)G * E * T);  // 8192 floats
  float* gate = lse2 + (size_t)G * T;                // G*E*max_cap floats

  unsigned n4d = (unsigned)((long long)G * E * T * max_cap / 4);  // per array

  k1_zero_logits<<<ZK1 + LGB + PB, 256, 0, stream>>>(
      x, W, b, keys, lse2, gate, (float*)d_out, n4d, max_cap);
  k2_rank<<<256, 256, 0, stream>>>(keys, gate, (float*)d_out, max_cap, ec);

  int blocks = 6144;
  if (max_cap == 384) {
    k3_combine<96><<<blocks, 256, 0, stream>>>(gate, lse2, (float*)d_out, n4d,
                                               96u);
  } else {
    k3_combine<0><<<blocks, 256, 0, stream>>>(gate, lse2, (float*)d_out, n4d,
                                              (unsigned)(max_cap / 4));
  }
}

// Round 9
// 77.947 us; speedup vs baseline: 1.1357x; 1.1357x over previous
//
#include <hip/hip_runtime.h>
#include <hip/hip_bf16.h>
#include <math.h>

#define G 4
#define T 2048
#define H 1024
#define E 8
#define NBUK 2048  // 11-bit buckets (key>>53)
#define SELB 32    // K2 select blocks (one per g,e)
#define ZELB 448   // K2 zero-fill blocks

typedef float f4 __attribute__((ext_vector_type(4)));
typedef unsigned long long u64;

// ---------------------------------------------------------------------------
// K1: logits+softmax -> u64 keys (key = prob_bits<<32 | ~t : unique, desc ==
// (value desc, idx asc) == jax.lax.top_k). fp64 path + lane-parallel epilogue
// FROZEN (absmax=0.0 R2-R6, R8).
// ---------------------------------------------------------------------------
__global__ __launch_bounds__(256) void k1_logits(
    const float* __restrict__ x, const float* __restrict__ W,
    const float* __restrict__ b, u64* __restrict__ keys,
    float* __restrict__ lse2) {
  int wave = (int)(blockIdx.x * 4 + (threadIdx.x >> 6));
  int lane = (int)(threadIdx.x & 63);
  const float* xr = x + (size_t)wave * H;

  double acc0 = 0, acc1 = 0, acc2 = 0, acc3 = 0;
  double acc4 = 0, acc5 = 0, acc6 = 0, acc7 = 0;
#pragma unroll
  for (int j = 0; j < 4; ++j) {
    int hbase = j * 256 + lane * 4;
    f4 xv = *(const f4*)(xr + hbase);
#pragma unroll
    for (int k = 0; k < 4; ++k) {
      const float* wr = W + (size_t)(hbase + k) * 8;
      f4 w0 = *(const f4*)(wr);
      f4 w1 = *(const f4*)(wr + 4);
      double xd = (double)xv[k];
      acc0 += xd * (double)w0[0];
      acc1 += xd * (double)w0[1];
      acc2 += xd * (double)w0[2];
      acc3 += xd * (double)w0[3];
      acc4 += xd * (double)w1[0];
      acc5 += xd * (double)w1[1];
      acc6 += xd * (double)w1[2];
      acc7 += xd * (double)w1[3];
    }
  }
#pragma unroll
  for (int off = 32; off >= 1; off >>= 1) {
    acc0 += __shfl_xor(acc0, off);
    acc1 += __shfl_xor(acc1, off);
    acc2 += __shfl_xor(acc2, off);
    acc3 += __shfl_xor(acc3, off);
    acc4 += __shfl_xor(acc4, off);
    acc5 += __shfl_xor(acc5, off);
    acc6 += __shfl_xor(acc6, off);
    acc7 += __shfl_xor(acc7, off);
  }
  double l0 = acc0 + (double)b[0], l1 = acc1 + (double)b[1];
  double l2 = acc2 + (double)b[2], l3 = acc3 + (double)b[3];
  double l4 = acc4 + (double)b[4], l5 = acc5 + (double)b[5];
  double l6 = acc6 + (double)b[6], l7 = acc7 + (double)b[7];
  double m = fmax(fmax(fmax(l0, l1), fmax(l2, l3)),
                  fmax(fmax(l4, l5), fmax(l6, l7)));
  double la = (lane & 1) ? l1 : l0;
  double lb = (lane & 1) ? l3 : l2;
  double lc = (lane & 1) ? l5 : l4;
  double ld = (lane & 1) ? l7 : l6;
  double le = (lane & 2) ? lb : la;
  double lf = (lane & 2) ? ld : lc;
  double lsel = (lane & 4) ? lf : le;

  double pe = exp(lsel - m);
  double s = pe;
  s += __shfl_xor(s, 1);
  s += __shfl_xor(s, 2);
  s += __shfl_xor(s, 4);  // bitwise == reference's add tree
  double inv = 1.0 / s;
  float pf = (float)(pe * inv);

  int g = wave >> 11;
  int t = wave & (T - 1);
  if (lane < 8) {
    keys[((size_t)g * 8 + lane) * T + t] =
        ((u64)__float_as_uint(pf) << 32) | (unsigned)(~t);
  }
  if (lane == 0) {
    double lse = m + log(s);
    lse2[wave] = (float)(lse * lse);
  }
}

// ---------------------------------------------------------------------------
// K2 (FUSED): blocks [0,32) = exact radix-histogram select per (g,e)
// (R8 post-mortem: O(T^2) rank scan ~40us; histogram cuts 134M compares to
// the winner buckets only). blocks [32,480) = zero dispatch half (no race:
// select writes only gate/idx in ws). Select: histogram key>>53 (2048
// buckets) -> suffix scan (count of higher buckets) -> counting-scatter ->
// intra-bucket compare scan only where bucket offset < cap. Unique keys =>
// exact rank; slots 0..cap-1 each written exactly once.
// ---------------------------------------------------------------------------
__global__ __launch_bounds__(1024) void k2_select_zero(
    const u64* __restrict__ keys, float* __restrict__ gate,
    int* __restrict__ idx, float* __restrict__ out, unsigned n4d, int max_cap,
    int ec) {
  unsigned bid = blockIdx.x;
  unsigned tid = threadIdx.x;

  if (bid >= SELB) {
    f4* outD = (f4*)out;
    f4 z = {0.0f, 0.0f, 0.0f, 0.0f};
    unsigned stride = ZELB * 1024u;
    for (unsigned i = (bid - SELB) * 1024u + tid; i < n4d; i += stride)
      outD[i] = z;
    return;
  }

  __shared__ int hist[NBUK];
  __shared__ int sA[NBUK];
  __shared__ int sB[NBUK];
  __shared__ int cur[NBUK];
  __shared__ u64 srt[T];
  int ge = (int)bid;

  hist[tid] = 0;
  hist[tid + 1024] = 0;
  // pad-init gate/idx before any winner writes (barriers below order this)
  if (tid < (unsigned)max_cap) {
    gate[(size_t)ge * max_cap + tid] = 0.0f;
    idx[(size_t)ge * max_cap + tid] = -1;
  }
  __syncthreads();

  const u64* kcol = keys + (size_t)ge * T;
  u64 k0 = kcol[tid];
  u64 k1 = kcol[tid + 1024];
  int b0 = (int)(k0 >> 53);
  int b1 = (int)(k1 >> 53);
  atomicAdd(&hist[b0], 1);
  atomicAdd(&hist[b1], 1);
  __syncthreads();

  // suffix-inclusive scan: S[b] = sum_{b'>=b} hist[b']  (Hillis-Steele)
  sA[tid] = hist[tid];
  sA[tid + 1024] = hist[tid + 1024];
  __syncthreads();
  int* src = sA;
  int* dst = sB;
  for (int s = 1; s < NBUK; s <<= 1) {
    for (int i = (int)tid; i < NBUK; i += 1024) {
      int v = src[i];
      if (i + s < NBUK) v += src[i + s];
      dst[i] = v;
    }
    __syncthreads();
    int* tmp = src;
    src = dst;
    dst = tmp;
  }
  // src[b] = inclusive suffix; offset (rank base) = src[b]-hist[b]
  for (int i = (int)tid; i < NBUK; i += 1024) cur[i] = src[i] - hist[i];
  __syncthreads();

  int p0 = atomicAdd(&cur[b0], 1);
  srt[p0] = k0;
  int p1 = atomicAdd(&cur[b1], 1);
  srt[p1] = k1;
  __syncthreads();

  const double factors[8] = {0.5, 0.75, 1.0, 1.0, 1.25, 1.25, 1.5, 1.5};
  int cap = (int)((double)ec * factors[ge & 7]);

  int o0 = src[b0] - hist[b0];
  if (o0 < cap) {
    int end = src[b0];
    int c = 0;
    for (int i = o0; i < end; ++i) c += (int)(srt[i] > k0);
    int r = o0 + c;
    if (r < cap) {
      gate[(size_t)ge * max_cap + r] = __uint_as_float((unsigned)(k0 >> 32));
      idx[(size_t)ge * max_cap + r] = (int)~(unsigned)k0;
    }
  }
  int o1 = src[b1] - hist[b1];
  if (o1 < cap) {
    int end = src[b1];
    int c = 0;
    for (int i = o1; i < end; ++i) c += (int)(srt[i] > k1);
    int r = o1 + c;
    if (r < cap) {
      gate[(size_t)ge * max_cap + r] = __uint_as_float((unsigned)(k1 >> 32));
      idx[(size_t)ge * max_cap + r] = (int)~(unsigned)k1;
    }
  }
}

// ---------------------------------------------------------------------------
// K3: block 0 = z-loss; blocks [1,1+scb] = scatter ones via idx (dispatch
// pre-zeroed in K2); rest = combine broadcast-fill. (Proven R3/R4.)
// ---------------------------------------------------------------------------
template <int MC4S>
__global__ __launch_bounds__(256) void k3_scatter_combine(
    const float* __restrict__ gate, const int* __restrict__ idx,
    const float* __restrict__ lse2, float* __restrict__ out, unsigned n4d,
    unsigned mc4_rt, int max_cap, unsigned scb) {
  const unsigned mc4 = MC4S ? (unsigned)MC4S : mc4_rt;
  unsigned tid = threadIdx.x;
  unsigned bid = blockIdx.x;

  if (bid == 0) {
    __shared__ double red[256];
    double s = 0.0;
    for (int i = tid; i < G * T; i += 256) s += (double)lse2[i];
    red[tid] = s;
    __syncthreads();
    for (int off = 128; off > 0; off >>= 1) {
      if ((int)tid < off) red[tid] += red[tid + off];
      __syncthreads();
    }
    if (tid == 0) {
      size_t ne = (size_t)n4d * 4;
      out[2 * ne] = 0.0f;                                   // auxiliary_loss
      out[2 * ne + 1] = (float)(red[0] / (double)(G * T));  // z_loss
    }
    return;
  }
  if (bid <= scb) {
    unsigned s = (bid - 1) * 256u + tid;
    if (s < (unsigned)(G * E) * (unsigned)max_cap) {
      unsigned ge = s / (unsigned)max_cap;
      unsigned c = s - ge * (unsigned)max_cap;
      int t = idx[s];
      if (t >= 0) out[((size_t)ge * T + t) * (unsigned)max_cap + c] = 1.0f;
    }
    return;
  }

  f4* outC = (f4*)out + n4d;
  const f4* gate4 = (const f4*)gate;
  unsigned fb = bid - 1 - scb;
  unsigned nfb = gridDim.x - 1 - scb;
  unsigned stride = nfb * 256u;
  for (unsigned i = fb * 256u + tid; i < n4d; i += stride) {
    unsigned c4 = i % mc4;
    unsigned ge = (i / mc4) >> 11;
    outC[i] = gate4[ge * mc4 + c4];
  }
}

extern "C" void kernel_launch(void* const* d_in, const int* in_sizes, int n_in,
                              void* d_out, int out_size, void* d_ws,
                              size_t ws_size, hipStream_t stream) {
  const float* x = (const float*)d_in[0];
  const float* W = (const float*)d_in[1];
  const float* b = (const float*)d_in[2];

  // Derive max_cap from out_size: out = 2*G*E*T*max_cap + 2 scalars.
  long long body = (long long)out_size - 2;
  int max_cap = (int)(body / (2LL * G * E * T));  // 384 for ec=256
  if (max_cap <= 0) return;
  int ec = (2 * max_cap) / 3;  // max factor is 1.5

  u64* keys = (u64*)d_ws;                            // 32*2048 u64 = 512 KB
  float* lse2 = (float*)(keys + (size_t)G * E * T);  // 8192 floats
  float* gate = lse2 + (size_t)G * T;                // G*E*max_cap floats
  int* idx = (int*)(gate + (size_t)G * E * max_cap);

  unsigned n4d = (unsigned)((long long)G * E * T * max_cap / 4);  // per array
  unsigned scb = (unsigned)((G * E * max_cap + 255) / 256);       // 48

  k1_logits<<<G * T / 4, 256, 0, stream>>>(x, W, b, keys, lse2);
  k2_select_zero<<<SELB + ZELB, 1024, 0, stream>>>(keys, gate, idx,
                                                   (float*)d_out, n4d, max_cap,
                                                   ec);
  int blocks = 6144;
  if (max_cap == 384) {
    k3_scatter_combine<96><<<blocks, 256, 0, stream>>>(
        gate, idx, lse2, (float*)d_out, n4d, 96u, max_cap, scb);
  } else {
    k3_scatter_combine<0><<<blocks, 256, 0, stream>>>(
        gate, idx, lse2, (float*)d_out, n4d, (unsigned)(max_cap / 4), max_cap,
        scb);
  }
}